// Round 5
// baseline (2947.227 us; speedup 1.0000x reference)
//
#include <hip/hip_runtime.h>
#include <stdint.h>

#define DIM 128

// sums[i][:] = X[i][:]  (self edge), counts[i] = 1
__global__ void k_init(const float4* __restrict__ X4, float4* __restrict__ sums4,
                       float* __restrict__ counts, int n4, int N) {
    int t = blockIdx.x * blockDim.x + threadIdx.x;
    if (t < n4) sums4[t] = X4[t];
    if (t < N) counts[t] = 1.0f;
}

// one edge per 32 lanes; each lane gathers float4 and atomically adds into sums
__global__ void k_scatter(const float4* __restrict__ X4, const int* __restrict__ adj,
                          float* __restrict__ sums, float* __restrict__ counts,
                          int E, int N) {
    int idx = blockIdx.x * blockDim.x + threadIdx.x;
    int e = idx >> 5;
    int lane = idx & 31;
    if (e >= E) return;
    int s  = adj[e];        // destination (segment id)
    int nb = adj[E + e];    // neighbor to gather
    if ((unsigned)s >= (unsigned)N || (unsigned)nb >= (unsigned)N) return;  // defensive
    float4 v = X4[(size_t)nb * 32 + lane];
    float* dst = sums + (size_t)s * DIM + lane * 4;
    atomicAdd(dst + 0, v.x);
    atomicAdd(dst + 1, v.y);
    atomicAdd(dst + 2, v.z);
    atomicAdd(dst + 3, v.w);
    if (lane == 0) atomicAdd(counts + s, 1.0f);
}

// out[i][:] = (sums[i][:] / counts[i]) @ W ; W fp32 in LDS (64 KiB); fp32 output
__global__ void __launch_bounds__(256) k_project(const float* __restrict__ sums,
                                                 const float* __restrict__ counts,
                                                 const float* __restrict__ W,
                                                 float* __restrict__ out, int N) {
    __shared__ float Wl[DIM * DIM];      // 64 KiB
    __shared__ float rows[8][DIM];       // 4 KiB
    int t = threadIdx.x;
    for (int i = t; i < DIM * (DIM / 4); i += 256) {
        ((float4*)Wl)[i] = ((const float4*)W)[i];
    }
    __syncthreads();
    int r = t >> 5;   // row within 8-row tile
    int c = t & 31;   // float4 column index
    for (int base = blockIdx.x * 8; base < N; base += gridDim.x * 8) {
        int row = base + r;
        if (row < N) {
            float inv = 1.0f / counts[row];
            float4 v = ((const float4*)sums)[(size_t)row * 32 + c];
            ((float4*)rows[r])[c] = make_float4(v.x * inv, v.y * inv, v.z * inv, v.w * inv);
        }
        __syncthreads();
        if (row < N) {
            float a0 = 0.f, a1 = 0.f, a2 = 0.f, a3 = 0.f;
            #pragma unroll 8
            for (int d = 0; d < DIM; ++d) {
                float m = rows[r][d];
                float4 w = ((const float4*)(Wl + d * DIM))[c];
                a0 = fmaf(m, w.x, a0);
                a1 = fmaf(m, w.y, a1);
                a2 = fmaf(m, w.z, a2);
                a3 = fmaf(m, w.w, a3);
            }
            ((float4*)out)[(size_t)row * 32 + c] = make_float4(a0, a1, a2, a3);
        }
        __syncthreads();
    }
}

extern "C" void kernel_launch(void* const* d_in, const int* in_sizes, int n_in,
                              void* d_out, int out_size, void* d_ws, size_t ws_size,
                              hipStream_t stream) {
    int N = in_sizes[0] / DIM;   // 100000
    int E = in_sizes[1] / 2;     // 1600000
    const float* X = (const float*)d_in[0];
    const int* adj = (const int*)d_in[1];   // int32 on device (harness converts integers)
    const float* W = (const float*)d_in[2];
    float* out = (float*)d_out;             // fp32 output

    float* sums   = (float*)d_ws;                  // N*128 fp32 = 51.2 MB
    float* counts = sums + (size_t)N * DIM;        // N fp32

    int n4 = N * (DIM / 4);
    k_init<<<(n4 + 255) / 256, 256, 0, stream>>>((const float4*)X, (float4*)sums, counts, n4, N);

    long long sthreads = (long long)E * 32;
    k_scatter<<<(int)((sthreads + 255) / 256), 256, 0, stream>>>(
        (const float4*)X, adj, sums, counts, E, N);

    k_project<<<512, 256, 0, stream>>>(sums, counts, W, out, N);
}

// Round 6
// 718.876 us; speedup vs baseline: 4.0998x; 4.0998x over previous
//
#include <hip/hip_runtime.h>
#include <stdint.h>

#define DIM 128
#define SCAN_THREADS 1024

__global__ void k_zero(int* __restrict__ p, int n) {
    int t = blockIdx.x * blockDim.x + threadIdx.x;
    if (t < n) p[t] = 0;
}

// histogram of destinations into counts (== cursor buffer)
__global__ void k_hist(const int* __restrict__ adj, int* __restrict__ counts, int E, int N) {
    int e = blockIdx.x * blockDim.x + threadIdx.x;
    if (e >= E) return;
    int d = adj[e];
    if ((unsigned)d < (unsigned)N) atomicAdd(&counts[d], 1);
}

// single-block exclusive scan: counts (aliased cursor) -> offsets[0..N], cursor[i]=offsets[i]
__global__ void __launch_bounds__(SCAN_THREADS) k_scan(int* __restrict__ counts /*==cursor*/,
                                                       int* __restrict__ offsets, int N) {
    __shared__ int lds[SCAN_THREADS];
    int t = threadIdx.x;
    int chunk = (N + SCAN_THREADS - 1) / SCAN_THREADS;
    int lo = t * chunk, hi = min(N, lo + chunk);
    int s = 0;
    for (int i = lo; i < hi; ++i) s += counts[i];
    lds[t] = s;
    __syncthreads();
    // inclusive Hillis-Steele scan over 1024 partials
    for (int off = 1; off < SCAN_THREADS; off <<= 1) {
        int v = (t >= off) ? lds[t - off] : 0;
        __syncthreads();
        lds[t] += v;
        __syncthreads();
    }
    int running = (t == 0) ? 0 : lds[t - 1];
    for (int i = lo; i < hi; ++i) {
        int c = counts[i];     // read BEFORE overwrite (aliased)
        offsets[i] = running;
        counts[i] = running;   // cursor init for reorder
        running += c;
    }
    if (t == SCAN_THREADS - 1) offsets[N] = lds[SCAN_THREADS - 1];
}

// place each edge's neighbor id into destination-sorted order
__global__ void k_reorder(const int* __restrict__ adj, int* __restrict__ cursor,
                          int* __restrict__ sorted_nbr, int E, int N) {
    int e = blockIdx.x * blockDim.x + threadIdx.x;
    if (e >= E) return;
    int d = adj[e];
    if ((unsigned)d >= (unsigned)N) return;
    int nb = adj[E + e];
    int pos = atomicAdd(&cursor[d], 1);
    sorted_nbr[pos] = ((unsigned)nb < (unsigned)N) ? nb : 0;
}

// one 64-lane wave per destination: register-accumulate its contiguous segment, write mean once
__global__ void __launch_bounds__(256) k_aggregate(const float2* __restrict__ X2,
                                                   const int* __restrict__ offsets,
                                                   const int* __restrict__ sorted_nbr,
                                                   float2* __restrict__ mean2, int N) {
    int wid = (blockIdx.x * blockDim.x + threadIdx.x) >> 6;  // wave id == dst node
    int lane = threadIdx.x & 63;                             // 64 lanes x float2 = 128 dims
    if (wid >= N) return;
    int beg = offsets[wid], end = offsets[wid + 1];
    float2 acc = X2[(size_t)wid * 64 + lane];                // self edge
    int e = beg;
    for (; e + 1 < end; e += 2) {                            // 2-way unroll for load latency
        int n0 = sorted_nbr[e], n1 = sorted_nbr[e + 1];
        float2 v0 = X2[(size_t)n0 * 64 + lane];
        float2 v1 = X2[(size_t)n1 * 64 + lane];
        acc.x += v0.x + v1.x;
        acc.y += v0.y + v1.y;
    }
    if (e < end) {
        int n0 = sorted_nbr[e];
        float2 v0 = X2[(size_t)n0 * 64 + lane];
        acc.x += v0.x;
        acc.y += v0.y;
    }
    float inv = 1.0f / (float)(end - beg + 1);
    mean2[(size_t)wid * 64 + lane] = make_float2(acc.x * inv, acc.y * inv);
}

// in-place row-wise projection: mo[i][:] = mo[i][:] @ W ; W fp32 in LDS (64 KiB)
__global__ void __launch_bounds__(256) k_project(float* mo, const float* __restrict__ W, int N) {
    __shared__ float Wl[DIM * DIM];
    __shared__ float rows[8][DIM];
    int t = threadIdx.x;
    for (int i = t; i < DIM * (DIM / 4); i += 256) {
        ((float4*)Wl)[i] = ((const float4*)W)[i];
    }
    __syncthreads();
    int r = t >> 5;   // row within 8-row tile
    int c = t & 31;   // float4 column index
    for (int base = blockIdx.x * 8; base < N; base += gridDim.x * 8) {
        int row = base + r;
        if (row < N) {
            ((float4*)rows[r])[c] = ((const float4*)mo)[(size_t)row * 32 + c];
        }
        __syncthreads();   // full row staged before any overwrite
        if (row < N) {
            float a0 = 0.f, a1 = 0.f, a2 = 0.f, a3 = 0.f;
            #pragma unroll 8
            for (int d = 0; d < DIM; ++d) {
                float m = rows[r][d];
                float4 w = ((const float4*)(Wl + d * DIM))[c];
                a0 = fmaf(m, w.x, a0);
                a1 = fmaf(m, w.y, a1);
                a2 = fmaf(m, w.z, a2);
                a3 = fmaf(m, w.w, a3);
            }
            ((float4*)mo)[(size_t)row * 32 + c] = make_float4(a0, a1, a2, a3);
        }
        __syncthreads();
    }
}

extern "C" void kernel_launch(void* const* d_in, const int* in_sizes, int n_in,
                              void* d_out, int out_size, void* d_ws, size_t ws_size,
                              hipStream_t stream) {
    int N = in_sizes[0] / DIM;   // 100000
    int E = in_sizes[1] / 2;     // 1600000
    const float* X = (const float*)d_in[0];
    const int* adj = (const int*)d_in[1];
    const float* W = (const float*)d_in[2];
    float* out = (float*)d_out;  // fp32; also used as the mean buffer

    // workspace: cursor[N] | offsets[N+1] | sorted_nbr[E]  (~7.2 MB)
    int* cursor     = (int*)d_ws;
    int* offsets    = cursor + N;
    int* sorted_nbr = offsets + (N + 1);

    k_zero<<<(N + 255) / 256, 256, 0, stream>>>(cursor, N);
    k_hist<<<(E + 255) / 256, 256, 0, stream>>>(adj, cursor, E, N);
    k_scan<<<1, SCAN_THREADS, 0, stream>>>(cursor, offsets, N);
    k_reorder<<<(E + 255) / 256, 256, 0, stream>>>(adj, cursor, sorted_nbr, E, N);

    // one wave per destination, 4 waves per block
    int agg_blocks = (N + 3) / 4;
    k_aggregate<<<agg_blocks, 256, 0, stream>>>((const float2*)X, offsets, sorted_nbr,
                                                (float2*)out, N);

    k_project<<<512, 256, 0, stream>>>(out, W, N);
}

// Round 7
// 488.050 us; speedup vs baseline: 6.0388x; 1.4730x over previous
//
#include <hip/hip_runtime.h>
#include <stdint.h>

#define DIM 128
#define SB 256   // scan block size

__global__ void k_zero(int* __restrict__ p, int n) {
    int t = blockIdx.x * blockDim.x + threadIdx.x;
    if (t < n) p[t] = 0;
}

// histogram of destinations into counts (== cursor buffer)
__global__ void k_hist(const int* __restrict__ adj, int* __restrict__ counts, int E, int N) {
    int e = blockIdx.x * blockDim.x + threadIdx.x;
    if (e >= E) return;
    int d = adj[e];
    if ((unsigned)d < (unsigned)N) atomicAdd(&counts[d], 1);
}

// scan phase A: per-block sums of counts -> partials[b]
__global__ void __launch_bounds__(SB) k_bsum(const int* __restrict__ counts,
                                             int* __restrict__ partials, int N) {
    __shared__ int lds[SB];
    int t = threadIdx.x;
    int i = blockIdx.x * SB + t;
    lds[t] = (i < N) ? counts[i] : 0;
    __syncthreads();
    for (int off = SB / 2; off > 0; off >>= 1) {
        if (t < off) lds[t] += lds[t + off];
        __syncthreads();
    }
    if (t == 0) partials[blockIdx.x] = lds[0];
}

// scan phase B: single block scans partials (-> exclusive), total -> offsets[N]
__global__ void __launch_bounds__(1024) k_pscan(int* __restrict__ partials,
                                                int* __restrict__ offsets, int nb, int N) {
    __shared__ int lds[1024];
    int t = threadIdx.x;
    int v0 = (t < nb) ? partials[t] : 0;
    lds[t] = v0;
    __syncthreads();
    for (int off = 1; off < 1024; off <<= 1) {
        int v = (t >= off) ? lds[t - off] : 0;
        __syncthreads();
        lds[t] += v;
        __syncthreads();
    }
    if (t < nb) partials[t] = lds[t] - v0;   // exclusive
    if (t == 1023) offsets[N] = lds[1023];
}

// scan phase C: intra-block exclusive scan + block base -> offsets[i], cursor[i]
// (counts_in aliases cursor: reads complete before writes within the block; blocks disjoint)
__global__ void __launch_bounds__(SB) k_scan_final(const int* __restrict__ counts_in,
                                                   const int* __restrict__ partials,
                                                   int* __restrict__ offsets,
                                                   int* __restrict__ cursor, int N) {
    __shared__ int lds[SB];
    int t = threadIdx.x;
    int i = blockIdx.x * SB + t;
    int c = (i < N) ? counts_in[i] : 0;
    lds[t] = c;
    __syncthreads();
    for (int off = 1; off < SB; off <<= 1) {
        int v = (t >= off) ? lds[t - off] : 0;
        __syncthreads();
        lds[t] += v;
        __syncthreads();
    }
    int excl = lds[t] - c + partials[blockIdx.x];
    if (i < N) {
        offsets[i] = excl;
        cursor[i] = excl;
    }
}

// place each edge's neighbor id into destination-sorted order
__global__ void k_reorder(const int* __restrict__ adj, int* __restrict__ cursor,
                          int* __restrict__ sorted_nbr, int E, int N) {
    int e = blockIdx.x * blockDim.x + threadIdx.x;
    if (e >= E) return;
    int d = adj[e];
    if ((unsigned)d >= (unsigned)N) return;
    int nb = adj[E + e];
    int pos = atomicAdd(&cursor[d], 1);
    sorted_nbr[pos] = ((unsigned)nb < (unsigned)N) ? nb : 0;
}

// one 64-lane wave per destination: register-accumulate contiguous segment, write mean once
__global__ void __launch_bounds__(256) k_aggregate(const float2* __restrict__ X2,
                                                   const int* __restrict__ offsets,
                                                   const int* __restrict__ sorted_nbr,
                                                   float2* __restrict__ mean2, int N) {
    int wid = (blockIdx.x * blockDim.x + threadIdx.x) >> 6;  // wave id == dst node
    int lane = threadIdx.x & 63;                             // 64 lanes x float2 = 128 dims
    if (wid >= N) return;
    int beg = offsets[wid], end = offsets[wid + 1];
    float2 acc = X2[(size_t)wid * 64 + lane];                // self edge
    int e = beg;
    for (; e + 3 < end; e += 4) {                            // 4-way unroll: hide gather latency
        int n0 = sorted_nbr[e], n1 = sorted_nbr[e + 1];
        int n2 = sorted_nbr[e + 2], n3 = sorted_nbr[e + 3];
        float2 v0 = X2[(size_t)n0 * 64 + lane];
        float2 v1 = X2[(size_t)n1 * 64 + lane];
        float2 v2 = X2[(size_t)n2 * 64 + lane];
        float2 v3 = X2[(size_t)n3 * 64 + lane];
        acc.x += (v0.x + v1.x) + (v2.x + v3.x);
        acc.y += (v0.y + v1.y) + (v2.y + v3.y);
    }
    for (; e < end; ++e) {
        int n0 = sorted_nbr[e];
        float2 v0 = X2[(size_t)n0 * 64 + lane];
        acc.x += v0.x;
        acc.y += v0.y;
    }
    float inv = 1.0f / (float)(end - beg + 1);
    mean2[(size_t)wid * 64 + lane] = make_float2(acc.x * inv, acc.y * inv);
}

// in-place row-wise projection: mo[i][:] = mo[i][:] @ W ; W fp32 in LDS (64 KiB)
__global__ void __launch_bounds__(256) k_project(float* mo, const float* __restrict__ W, int N) {
    __shared__ float Wl[DIM * DIM];
    __shared__ float rows[8][DIM];
    int t = threadIdx.x;
    for (int i = t; i < DIM * (DIM / 4); i += 256) {
        ((float4*)Wl)[i] = ((const float4*)W)[i];
    }
    __syncthreads();
    int r = t >> 5;
    int c = t & 31;
    for (int base = blockIdx.x * 8; base < N; base += gridDim.x * 8) {
        int row = base + r;
        if (row < N) {
            ((float4*)rows[r])[c] = ((const float4*)mo)[(size_t)row * 32 + c];
        }
        __syncthreads();   // full row staged before any overwrite
        if (row < N) {
            float a0 = 0.f, a1 = 0.f, a2 = 0.f, a3 = 0.f;
            #pragma unroll 8
            for (int d = 0; d < DIM; ++d) {
                float m = rows[r][d];
                float4 w = ((const float4*)(Wl + d * DIM))[c];
                a0 = fmaf(m, w.x, a0);
                a1 = fmaf(m, w.y, a1);
                a2 = fmaf(m, w.z, a2);
                a3 = fmaf(m, w.w, a3);
            }
            ((float4*)mo)[(size_t)row * 32 + c] = make_float4(a0, a1, a2, a3);
        }
        __syncthreads();
    }
}

extern "C" void kernel_launch(void* const* d_in, const int* in_sizes, int n_in,
                              void* d_out, int out_size, void* d_ws, size_t ws_size,
                              hipStream_t stream) {
    int N = in_sizes[0] / DIM;   // 100000
    int E = in_sizes[1] / 2;     // 1600000
    const float* X = (const float*)d_in[0];
    const int* adj = (const int*)d_in[1];
    const float* W = (const float*)d_in[2];
    float* out = (float*)d_out;  // fp32; also the mean buffer

    int nb = (N + SB - 1) / SB;  // 391 scan blocks

    // workspace: cursor[N] | offsets[N+1] | sorted_nbr[E] | partials[nb]
    int* cursor     = (int*)d_ws;
    int* offsets    = cursor + N;
    int* sorted_nbr = offsets + (N + 1);
    int* partials   = sorted_nbr + E;

    k_zero<<<(N + 255) / 256, 256, 0, stream>>>(cursor, N);
    k_hist<<<(E + 255) / 256, 256, 0, stream>>>(adj, cursor, E, N);
    k_bsum<<<nb, SB, 0, stream>>>(cursor, partials, N);
    k_pscan<<<1, 1024, 0, stream>>>(partials, offsets, nb, N);
    k_scan_final<<<nb, SB, 0, stream>>>(cursor, partials, offsets, cursor, N);
    k_reorder<<<(E + 255) / 256, 256, 0, stream>>>(adj, cursor, sorted_nbr, E, N);

    int agg_blocks = (N + 3) / 4;   // one wave per destination, 4 waves/block
    k_aggregate<<<agg_blocks, 256, 0, stream>>>((const float2*)X, offsets, sorted_nbr,
                                                (float2*)out, N);

    k_project<<<512, 256, 0, stream>>>(out, W, N);
}

// Round 8
// 391.884 us; speedup vs baseline: 7.5207x; 1.2454x over previous
//
#include <hip/hip_runtime.h>
#include <stdint.h>

#define DIM 128
#define SB 256   // scan block size

typedef unsigned short u16;
typedef unsigned int u32;
typedef __attribute__((ext_vector_type(8))) short short8;   // 8 bf16 (4 VGPRs)
typedef __attribute__((ext_vector_type(4))) float floatx4;  // MFMA C/D

__device__ __forceinline__ u16 f2bf(float f) {
    u32 u = __float_as_uint(f);
    if ((u & 0x7fffffffu) > 0x7f800000u) return (u16)0x7fc0;   // NaN-safe
    return (u16)((u + 0x7fffu + ((u >> 16) & 1u)) >> 16);      // RNE
}

__global__ void k_zero(int* __restrict__ p, int n) {
    int t = blockIdx.x * blockDim.x + threadIdx.x;
    if (t < n) p[t] = 0;
}

// dst-range-partitioned histogram: block handles range (blockIdx & 7) only,
// so each XCD's L2 owns 1/8 of the counts array (blockIdx%8 -> XCD heuristic).
__global__ void __launch_bounds__(256) k_hist(const int* __restrict__ adj,
                                              int* __restrict__ counts, int E, int N) {
    int r = blockIdx.x & 7;
    int sub = blockIdx.x >> 3;
    int nsub = gridDim.x >> 3;
    int lo = N / 8 * r + min(r, N % 8);
    int hi = lo + N / 8 + (r < N % 8 ? 1 : 0);
    for (int e = sub * 256 + threadIdx.x; e < E; e += nsub * 256) {
        int d = adj[e];
        if (d >= lo && d < hi) atomicAdd(&counts[d], 1);
    }
}

// scan phase A: per-block sums of counts -> partials[b]
__global__ void __launch_bounds__(SB) k_bsum(const int* __restrict__ counts,
                                             int* __restrict__ partials, int N) {
    __shared__ int lds[SB];
    int t = threadIdx.x;
    int i = blockIdx.x * SB + t;
    lds[t] = (i < N) ? counts[i] : 0;
    __syncthreads();
    for (int off = SB / 2; off > 0; off >>= 1) {
        if (t < off) lds[t] += lds[t + off];
        __syncthreads();
    }
    if (t == 0) partials[blockIdx.x] = lds[0];
}

// scan phase B: single block scans partials (-> exclusive), total -> offsets[N]
__global__ void __launch_bounds__(1024) k_pscan(int* __restrict__ partials,
                                                int* __restrict__ offsets, int nb, int N) {
    __shared__ int lds[1024];
    int t = threadIdx.x;
    int v0 = (t < nb) ? partials[t] : 0;
    lds[t] = v0;
    __syncthreads();
    for (int off = 1; off < 1024; off <<= 1) {
        int v = (t >= off) ? lds[t - off] : 0;
        __syncthreads();
        lds[t] += v;
        __syncthreads();
    }
    if (t < nb) partials[t] = lds[t] - v0;   // exclusive
    if (t == 1023) offsets[N] = lds[1023];
}

// scan phase C: intra-block exclusive scan + block base -> offsets[i], cursor[i]
__global__ void __launch_bounds__(SB) k_scan_final(const int* __restrict__ counts_in,
                                                   const int* __restrict__ partials,
                                                   int* __restrict__ offsets,
                                                   int* __restrict__ cursor, int N) {
    __shared__ int lds[SB];
    int t = threadIdx.x;
    int i = blockIdx.x * SB + t;
    int c = (i < N) ? counts_in[i] : 0;
    lds[t] = c;
    __syncthreads();
    for (int off = 1; off < SB; off <<= 1) {
        int v = (t >= off) ? lds[t - off] : 0;
        __syncthreads();
        lds[t] += v;
        __syncthreads();
    }
    int excl = lds[t] - c + partials[blockIdx.x];
    if (i < N) {
        offsets[i] = excl;
        cursor[i] = excl;
    }
}

// dst-range-partitioned reorder: writes for range r land in one contiguous
// ~E/8 region whose lines stay in one XCD's L2 (kills the 16x write amplification)
__global__ void __launch_bounds__(256) k_reorder(const int* __restrict__ adj,
                                                 int* __restrict__ cursor,
                                                 int* __restrict__ sorted_nbr, int E, int N) {
    int r = blockIdx.x & 7;
    int sub = blockIdx.x >> 3;
    int nsub = gridDim.x >> 3;
    int lo = N / 8 * r + min(r, N % 8);
    int hi = lo + N / 8 + (r < N % 8 ? 1 : 0);
    for (int e = sub * 256 + threadIdx.x; e < E; e += nsub * 256) {
        int d = adj[e];
        if (d < lo || d >= hi) continue;
        int nb = adj[E + e];
        int pos = atomicAdd(&cursor[d], 1);
        sorted_nbr[pos] = ((unsigned)nb < (unsigned)N) ? nb : 0;
    }
}

// one 64-lane wave per destination: register-accumulate contiguous segment, write mean once
__global__ void __launch_bounds__(256) k_aggregate(const float2* __restrict__ X2,
                                                   const int* __restrict__ offsets,
                                                   const int* __restrict__ sorted_nbr,
                                                   float2* __restrict__ mean2, int N) {
    int wid = (blockIdx.x * blockDim.x + threadIdx.x) >> 6;
    int lane = threadIdx.x & 63;
    if (wid >= N) return;
    int beg = offsets[wid], end = offsets[wid + 1];
    float2 acc = X2[(size_t)wid * 64 + lane];   // self edge
    int e = beg;
    for (; e + 3 < end; e += 4) {
        int n0 = sorted_nbr[e], n1 = sorted_nbr[e + 1];
        int n2 = sorted_nbr[e + 2], n3 = sorted_nbr[e + 3];
        float2 v0 = X2[(size_t)n0 * 64 + lane];
        float2 v1 = X2[(size_t)n1 * 64 + lane];
        float2 v2 = X2[(size_t)n2 * 64 + lane];
        float2 v3 = X2[(size_t)n3 * 64 + lane];
        acc.x += (v0.x + v1.x) + (v2.x + v3.x);
        acc.y += (v0.y + v1.y) + (v2.y + v3.y);
    }
    for (; e < end; ++e) {
        int n0 = sorted_nbr[e];
        float2 v0 = X2[(size_t)n0 * 64 + lane];
        acc.x += v0.x;
        acc.y += v0.y;
    }
    float inv = 1.0f / (float)(end - beg + 1);
    mean2[(size_t)wid * 64 + lane] = make_float2(acc.x * inv, acc.y * inv);
}

// MFMA projection, in-place on `mean`(==out): each wave owns 16 rows.
// A layout: lane holds A[m=lane&15][k=quad*8+j]; D: row=quad*4+reg, col=lane&15.
// LDS stride 136 (bf16) breaks the power-of-2 bank stride (272B = 17*16B).
__global__ void __launch_bounds__(256) k_project_mfma(float* __restrict__ mo,
                                                      const float* __restrict__ W, int N) {
    __shared__ __align__(16) u16 wt[DIM * 136];        // W^T bf16, padded (34 KB)
    __shared__ __align__(16) u16 a_lds[4][16 * 136];   // per-wave A tiles (34 KB)
    int t = threadIdx.x;
    // stage W^T bf16 (coalesced global reads: consecutive t -> consecutive n)
    for (int i = t; i < DIM * DIM; i += 256) {
        int n = i & 127, k = i >> 7;
        wt[n * 136 + k] = f2bf(W[k * DIM + n]);
    }
    __syncthreads();
    int w = t >> 6, l = t & 63;
    int q = l >> 4, c = l & 15;
    int row0 = (blockIdx.x * 4 + w) * 16;
    // stage this wave's 16 rows as bf16 A tile
    const float4* mo4 = (const float4*)mo;
    for (int rep = 0; rep < 8; ++rep) {
        int chunk = rep * 64 + l;
        int r = chunk >> 5, c4 = chunk & 31;
        int row = row0 + r;
        float4 v = (row < N) ? mo4[(size_t)row * 32 + c4] : make_float4(0.f, 0.f, 0.f, 0.f);
        ushort4 h;
        h.x = f2bf(v.x); h.y = f2bf(v.y); h.z = f2bf(v.z); h.w = f2bf(v.w);
        *(ushort4*)&a_lds[w][r * 136 + c4 * 4] = h;
    }
    __syncthreads();
    floatx4 acc[8] = {};
    #pragma unroll
    for (int kt = 0; kt < 4; ++kt) {
        short8 a = *(const short8*)&a_lds[w][c * 136 + kt * 32 + q * 8];
        #pragma unroll
        for (int nt = 0; nt < 8; ++nt) {
            short8 b = *(const short8*)&wt[(nt * 16 + c) * 136 + kt * 32 + q * 8];
            acc[nt] = __builtin_amdgcn_mfma_f32_16x16x32_bf16(a, b, acc[nt], 0, 0, 0);
        }
    }
    #pragma unroll
    for (int nt = 0; nt < 8; ++nt)
        #pragma unroll
        for (int r = 0; r < 4; ++r) {
            int row = row0 + q * 4 + r;
            if (row < N) mo[(size_t)row * DIM + nt * 16 + c] = acc[nt][r];
        }
}

extern "C" void kernel_launch(void* const* d_in, const int* in_sizes, int n_in,
                              void* d_out, int out_size, void* d_ws, size_t ws_size,
                              hipStream_t stream) {
    int N = in_sizes[0] / DIM;   // 100000
    int E = in_sizes[1] / 2;     // 1600000
    const float* X = (const float*)d_in[0];
    const int* adj = (const int*)d_in[1];
    const float* W = (const float*)d_in[2];
    float* out = (float*)d_out;  // fp32; also the mean buffer (in-place projection)

    int nb = (N + SB - 1) / SB;  // 391 scan blocks

    // workspace: cursor[N] | offsets[N+1] | sorted_nbr[E] | partials[nb]
    int* cursor     = (int*)d_ws;
    int* offsets    = cursor + N;
    int* sorted_nbr = offsets + (N + 1);
    int* partials   = sorted_nbr + E;

    k_zero<<<(N + 255) / 256, 256, 0, stream>>>(cursor, N);
    k_hist<<<1024, 256, 0, stream>>>(adj, cursor, E, N);
    k_bsum<<<nb, SB, 0, stream>>>(cursor, partials, N);
    k_pscan<<<1, 1024, 0, stream>>>(partials, offsets, nb, N);
    k_scan_final<<<nb, SB, 0, stream>>>(cursor, partials, offsets, cursor, N);
    k_reorder<<<1024, 256, 0, stream>>>(adj, cursor, sorted_nbr, E, N);

    int agg_blocks = (N + 3) / 4;   // one wave per destination, 4 waves/block
    k_aggregate<<<agg_blocks, 256, 0, stream>>>((const float2*)X, offsets, sorted_nbr,
                                                (float2*)out, N);

    int proj_blocks = (N + 63) / 64;  // 64 rows per block (4 waves x 16)
    k_project_mfma<<<proj_blocks, 256, 0, stream>>>(out, W, N);
}

// Round 9
// 374.819 us; speedup vs baseline: 7.8631x; 1.0455x over previous
//
#include <hip/hip_runtime.h>
#include <stdint.h>

#define DIM 128
#define SB 256   // scan block size

typedef unsigned short u16;
typedef unsigned int u32;
typedef __attribute__((ext_vector_type(8))) short short8;   // 8 bf16 (4 VGPRs)
typedef __attribute__((ext_vector_type(4))) float floatx4;  // MFMA C/D

__device__ __forceinline__ u16 f2bf(float f) {
    u32 u = __float_as_uint(f);
    if ((u & 0x7fffffffu) > 0x7f800000u) return (u16)0x7fc0;   // NaN-safe
    return (u16)((u + 0x7fffu + ((u >> 16) & 1u)) >> 16);      // RNE
}

// unpack 2 packed bf16 -> float2 (low u16 = even dim, high u16 = odd dim)
__device__ __forceinline__ float2 bfu(u32 u) {
    return make_float2(__uint_as_float(u << 16), __uint_as_float(u & 0xffff0000u));
}

// X fp32 -> bf16 cache in ws; also zeroes cursor (merged k_zero)
__global__ void k_convert_zero(const float4* __restrict__ X4, ushort4* __restrict__ Xb4,
                               int* __restrict__ cursor, int n4, int N) {
    int t = blockIdx.x * blockDim.x + threadIdx.x;
    if (t < n4) {
        float4 v = X4[t];
        ushort4 h;
        h.x = f2bf(v.x); h.y = f2bf(v.y); h.z = f2bf(v.z); h.w = f2bf(v.w);
        Xb4[t] = h;
    }
    if (t < N) cursor[t] = 0;
}

// dst-range-partitioned histogram (range blockIdx&7 -> XCD L2 locality)
__global__ void __launch_bounds__(256) k_hist(const int* __restrict__ adj,
                                              int* __restrict__ counts, int E, int N) {
    int r = blockIdx.x & 7;
    int sub = blockIdx.x >> 3;
    int nsub = gridDim.x >> 3;
    int lo = N / 8 * r + min(r, N % 8);
    int hi = lo + N / 8 + (r < N % 8 ? 1 : 0);
    for (int e = sub * 256 + threadIdx.x; e < E; e += nsub * 256) {
        int d = adj[e];
        if (d >= lo && d < hi) atomicAdd(&counts[d], 1);
    }
}

// scan phase A: per-block sums
__global__ void __launch_bounds__(SB) k_bsum(const int* __restrict__ counts,
                                             int* __restrict__ partials, int N) {
    __shared__ int lds[SB];
    int t = threadIdx.x;
    int i = blockIdx.x * SB + t;
    lds[t] = (i < N) ? counts[i] : 0;
    __syncthreads();
    for (int off = SB / 2; off > 0; off >>= 1) {
        if (t < off) lds[t] += lds[t + off];
        __syncthreads();
    }
    if (t == 0) partials[blockIdx.x] = lds[0];
}

// scan phase B: single block scans partials (-> exclusive), total -> offsets[N]
__global__ void __launch_bounds__(1024) k_pscan(int* __restrict__ partials,
                                                int* __restrict__ offsets, int nb, int N) {
    __shared__ int lds[1024];
    int t = threadIdx.x;
    int v0 = (t < nb) ? partials[t] : 0;
    lds[t] = v0;
    __syncthreads();
    for (int off = 1; off < 1024; off <<= 1) {
        int v = (t >= off) ? lds[t - off] : 0;
        __syncthreads();
        lds[t] += v;
        __syncthreads();
    }
    if (t < nb) partials[t] = lds[t] - v0;   // exclusive
    if (t == 1023) offsets[N] = lds[1023];
}

// scan phase C: intra-block exclusive scan + block base
__global__ void __launch_bounds__(SB) k_scan_final(const int* __restrict__ counts_in,
                                                   const int* __restrict__ partials,
                                                   int* __restrict__ offsets,
                                                   int* __restrict__ cursor, int N) {
    __shared__ int lds[SB];
    int t = threadIdx.x;
    int i = blockIdx.x * SB + t;
    int c = (i < N) ? counts_in[i] : 0;
    lds[t] = c;
    __syncthreads();
    for (int off = 1; off < SB; off <<= 1) {
        int v = (t >= off) ? lds[t - off] : 0;
        __syncthreads();
        lds[t] += v;
        __syncthreads();
    }
    int excl = lds[t] - c + partials[blockIdx.x];
    if (i < N) {
        offsets[i] = excl;
        cursor[i] = excl;
    }
}

// dst-range-partitioned reorder (XCD-local writes)
__global__ void __launch_bounds__(256) k_reorder(const int* __restrict__ adj,
                                                 int* __restrict__ cursor,
                                                 int* __restrict__ sorted_nbr, int E, int N) {
    int r = blockIdx.x & 7;
    int sub = blockIdx.x >> 3;
    int nsub = gridDim.x >> 3;
    int lo = N / 8 * r + min(r, N % 8);
    int hi = lo + N / 8 + (r < N % 8 ? 1 : 0);
    for (int e = sub * 256 + threadIdx.x; e < E; e += nsub * 256) {
        int d = adj[e];
        if (d < lo || d >= hi) continue;
        int nb = adj[E + e];
        int pos = atomicAdd(&cursor[d], 1);
        sorted_nbr[pos] = ((unsigned)nb < (unsigned)N) ? nb : 0;
    }
}

// one wave per destination; gathers bf16 rows (256 B each), fp32 accumulate, fp32 mean out
__global__ void __launch_bounds__(256) k_aggregate_bf(const u32* __restrict__ Xb,
                                                      const int* __restrict__ offsets,
                                                      const int* __restrict__ sorted_nbr,
                                                      float2* __restrict__ mean2, int N) {
    int wid = (blockIdx.x * blockDim.x + threadIdx.x) >> 6;
    int lane = threadIdx.x & 63;                 // lane holds dims 2*lane, 2*lane+1
    if (wid >= N) return;
    int beg = offsets[wid], end = offsets[wid + 1];
    float2 s = bfu(Xb[(size_t)wid * 64 + lane]);  // self edge
    float2 acc = make_float2(s.x, s.y);
    int e = beg;
    for (; e + 7 < end; e += 8) {                 // 8-way unroll: loads in flight
        int n0 = sorted_nbr[e],     n1 = sorted_nbr[e + 1];
        int n2 = sorted_nbr[e + 2], n3 = sorted_nbr[e + 3];
        int n4 = sorted_nbr[e + 4], n5 = sorted_nbr[e + 5];
        int n6 = sorted_nbr[e + 6], n7 = sorted_nbr[e + 7];
        u32 u0 = Xb[(size_t)n0 * 64 + lane], u1 = Xb[(size_t)n1 * 64 + lane];
        u32 u2 = Xb[(size_t)n2 * 64 + lane], u3 = Xb[(size_t)n3 * 64 + lane];
        u32 u4 = Xb[(size_t)n4 * 64 + lane], u5 = Xb[(size_t)n5 * 64 + lane];
        u32 u6 = Xb[(size_t)n6 * 64 + lane], u7 = Xb[(size_t)n7 * 64 + lane];
        float2 v0 = bfu(u0), v1 = bfu(u1), v2 = bfu(u2), v3 = bfu(u3);
        float2 v4 = bfu(u4), v5 = bfu(u5), v6 = bfu(u6), v7 = bfu(u7);
        acc.x += ((v0.x + v1.x) + (v2.x + v3.x)) + ((v4.x + v5.x) + (v6.x + v7.x));
        acc.y += ((v0.y + v1.y) + (v2.y + v3.y)) + ((v4.y + v5.y) + (v6.y + v7.y));
    }
    for (; e < end; ++e) {
        float2 v = bfu(Xb[(size_t)sorted_nbr[e] * 64 + lane]);
        acc.x += v.x;
        acc.y += v.y;
    }
    float inv = 1.0f / (float)(end - beg + 1);
    mean2[(size_t)wid * 64 + lane] = make_float2(acc.x * inv, acc.y * inv);
}

// MFMA projection, in-place on mean(==out); A: m=lane&15,k=quad*8+j; D: row=quad*4+reg,col=lane&15
__global__ void __launch_bounds__(256) k_project_mfma(float* __restrict__ mo,
                                                      const float* __restrict__ W, int N) {
    __shared__ __align__(16) u16 wt[DIM * 136];        // W^T bf16, padded
    __shared__ __align__(16) u16 a_lds[4][16 * 136];   // per-wave A tiles
    int t = threadIdx.x;
    for (int i = t; i < DIM * DIM; i += 256) {
        int n = i & 127, k = i >> 7;
        wt[n * 136 + k] = f2bf(W[k * DIM + n]);
    }
    __syncthreads();
    int w = t >> 6, l = t & 63;
    int q = l >> 4, c = l & 15;
    int row0 = (blockIdx.x * 4 + w) * 16;
    const float4* mo4 = (const float4*)mo;
    for (int rep = 0; rep < 8; ++rep) {
        int chunk = rep * 64 + l;
        int r = chunk >> 5, c4 = chunk & 31;
        int row = row0 + r;
        float4 v = (row < N) ? mo4[(size_t)row * 32 + c4] : make_float4(0.f, 0.f, 0.f, 0.f);
        ushort4 h;
        h.x = f2bf(v.x); h.y = f2bf(v.y); h.z = f2bf(v.z); h.w = f2bf(v.w);
        *(ushort4*)&a_lds[w][r * 136 + c4 * 4] = h;
    }
    __syncthreads();
    floatx4 acc[8] = {};
    #pragma unroll
    for (int kt = 0; kt < 4; ++kt) {
        short8 a = *(const short8*)&a_lds[w][c * 136 + kt * 32 + q * 8];
        #pragma unroll
        for (int nt = 0; nt < 8; ++nt) {
            short8 b = *(const short8*)&wt[(nt * 16 + c) * 136 + kt * 32 + q * 8];
            acc[nt] = __builtin_amdgcn_mfma_f32_16x16x32_bf16(a, b, acc[nt], 0, 0, 0);
        }
    }
    #pragma unroll
    for (int nt = 0; nt < 8; ++nt)
        #pragma unroll
        for (int r = 0; r < 4; ++r) {
            int row = row0 + q * 4 + r;
            if (row < N) mo[(size_t)row * DIM + nt * 16 + c] = acc[nt][r];
        }
}

extern "C" void kernel_launch(void* const* d_in, const int* in_sizes, int n_in,
                              void* d_out, int out_size, void* d_ws, size_t ws_size,
                              hipStream_t stream) {
    int N = in_sizes[0] / DIM;   // 100000
    int E = in_sizes[1] / 2;     // 1600000
    const float* X = (const float*)d_in[0];
    const int* adj = (const int*)d_in[1];
    const float* W = (const float*)d_in[2];
    float* out = (float*)d_out;  // fp32 mean buffer + in-place projection

    int nb = (N + SB - 1) / SB;  // 391 scan blocks

    // ws: cursor[N] | offsets[N+1] | sorted_nbr[E] | partials[512] | Xbf[N*DIM u16]  (~33 MB)
    int* cursor     = (int*)d_ws;
    int* offsets    = cursor + N;
    int* sorted_nbr = offsets + (N + 1);
    int* partials   = sorted_nbr + E;
    u16* Xbf        = (u16*)(partials + 512);

    int n4 = N * (DIM / 4);
    k_convert_zero<<<(n4 + 255) / 256, 256, 0, stream>>>(
        (const float4*)X, (ushort4*)Xbf, cursor, n4, N);
    k_hist<<<1024, 256, 0, stream>>>(adj, cursor, E, N);
    k_bsum<<<nb, SB, 0, stream>>>(cursor, partials, N);
    k_pscan<<<1, 1024, 0, stream>>>(partials, offsets, nb, N);
    k_scan_final<<<nb, SB, 0, stream>>>(cursor, partials, offsets, cursor, N);
    k_reorder<<<1024, 256, 0, stream>>>(adj, cursor, sorted_nbr, E, N);

    int agg_blocks = (N + 3) / 4;   // one wave per destination, 4 waves/block
    k_aggregate_bf<<<agg_blocks, 256, 0, stream>>>((const u32*)Xbf, offsets, sorted_nbr,
                                                   (float2*)out, N);

    int proj_blocks = (N + 63) / 64;  // 64 rows/block (4 waves x 16)
    k_project_mfma<<<proj_blocks, 256, 0, stream>>>(out, W, N);
}

// Round 10
// 360.769 us; speedup vs baseline: 8.1693x; 1.0389x over previous
//
#include <hip/hip_runtime.h>
#include <stdint.h>

#define DIM 128
#define SB 256   // scan block size

typedef unsigned short u16;
typedef unsigned int u32;
typedef __attribute__((ext_vector_type(8))) short short8;   // 8 bf16 (4 VGPRs)
typedef __attribute__((ext_vector_type(4))) float floatx4;  // MFMA C/D

__device__ __forceinline__ u16 f2bf(float f) {
    u32 u = __float_as_uint(f);
    if ((u & 0x7fffffffu) > 0x7f800000u) return (u16)0x7fc0;   // NaN-safe
    return (u16)((u + 0x7fffu + ((u >> 16) & 1u)) >> 16);      // RNE
}

// unpack 2 packed bf16 -> float2
__device__ __forceinline__ float2 bfu(u32 u) {
    return make_float2(__uint_as_float(u << 16), __uint_as_float(u & 0xffff0000u));
}

// Y = bf16(X @ W) via MFMA; also zeroes cursor. mean(X)@W == mean(X@W) (linearity),
// so projecting FIRST lets the aggregation write final fp32 output directly.
// A: m=lane&15, k=quad*8+j ; D: row=quad*4+reg, col=lane&15 (verified layouts).
__global__ void __launch_bounds__(256) k_gemm_y(const float4* __restrict__ X4,
                                                const float* __restrict__ W,
                                                u16* __restrict__ Ybf,
                                                int* __restrict__ cursor, int N) {
    __shared__ __align__(16) u16 wt[DIM * 136];        // W^T bf16, stride 136 (bank-safe)
    __shared__ __align__(16) u16 a_lds[4][16 * 136];   // per-wave A tile, reused for Y staging
    int t = threadIdx.x;
    int g = blockIdx.x * 256 + t;
    if (g < N) cursor[g] = 0;                          // fused k_zero
    for (int i = t; i < DIM * DIM; i += 256) {
        int n = i & 127, k = i >> 7;
        wt[n * 136 + k] = f2bf(W[k * DIM + n]);
    }
    __syncthreads();
    int w = t >> 6, l = t & 63;
    int q = l >> 4, c = l & 15;
    int row0 = (blockIdx.x * 4 + w) * 16;
    // stage 16 rows of X as bf16 A tile (coalesced float4 reads)
    #pragma unroll
    for (int rep = 0; rep < 8; ++rep) {
        int chunk = rep * 64 + l;
        int r = chunk >> 5, c4 = chunk & 31;
        int row = row0 + r;
        float4 v = (row < N) ? X4[(size_t)row * 32 + c4] : make_float4(0.f, 0.f, 0.f, 0.f);
        ushort4 h;
        h.x = f2bf(v.x); h.y = f2bf(v.y); h.z = f2bf(v.z); h.w = f2bf(v.w);
        *(ushort4*)&a_lds[w][r * 136 + c4 * 4] = h;
    }
    __syncthreads();
    floatx4 acc[8] = {};
    #pragma unroll
    for (int kt = 0; kt < 4; ++kt) {
        short8 a = *(const short8*)&a_lds[w][c * 136 + kt * 32 + q * 8];
        #pragma unroll
        for (int nt = 0; nt < 8; ++nt) {
            short8 b = *(const short8*)&wt[(nt * 16 + c) * 136 + kt * 32 + q * 8];
            acc[nt] = __builtin_amdgcn_mfma_f32_16x16x32_bf16(a, b, acc[nt], 0, 0, 0);
        }
    }
    // repack D (fp32) -> bf16 into this wave's a_lds region (wave-local, no barrier needed)
    #pragma unroll
    for (int nt = 0; nt < 8; ++nt)
        #pragma unroll
        for (int r = 0; r < 4; ++r)
            a_lds[w][(q * 4 + r) * 136 + nt * 16 + c] = f2bf(acc[nt][r]);
    // coalesced ushort4 stores of 16 Y rows
    #pragma unroll
    for (int rep = 0; rep < 8; ++rep) {
        int chunk = rep * 64 + l;
        int r = chunk >> 5, c4 = chunk & 31;
        int row = row0 + r;
        if (row < N)
            ((ushort4*)Ybf)[(size_t)row * 32 + c4] = *(ushort4*)&a_lds[w][r * 136 + c4 * 4];
    }
}

// dst-range-partitioned histogram (range blockIdx&7 -> XCD L2 locality)
__global__ void __launch_bounds__(256) k_hist(const int* __restrict__ adj,
                                              int* __restrict__ counts, int E, int N) {
    int r = blockIdx.x & 7;
    int sub = blockIdx.x >> 3;
    int nsub = gridDim.x >> 3;
    int lo = N / 8 * r + min(r, N % 8);
    int hi = lo + N / 8 + (r < N % 8 ? 1 : 0);
    for (int e = sub * 256 + threadIdx.x; e < E; e += nsub * 256) {
        int d = adj[e];
        if (d >= lo && d < hi) atomicAdd(&counts[d], 1);
    }
}

// scan phase A: per-block sums
__global__ void __launch_bounds__(SB) k_bsum(const int* __restrict__ counts,
                                             int* __restrict__ partials, int N) {
    __shared__ int lds[SB];
    int t = threadIdx.x;
    int i = blockIdx.x * SB + t;
    lds[t] = (i < N) ? counts[i] : 0;
    __syncthreads();
    for (int off = SB / 2; off > 0; off >>= 1) {
        if (t < off) lds[t] += lds[t + off];
        __syncthreads();
    }
    if (t == 0) partials[blockIdx.x] = lds[0];
}

// scan phase B: single block scans partials (-> exclusive), total -> offsets[N]
__global__ void __launch_bounds__(1024) k_pscan(int* __restrict__ partials,
                                                int* __restrict__ offsets, int nb, int N) {
    __shared__ int lds[1024];
    int t = threadIdx.x;
    int v0 = (t < nb) ? partials[t] : 0;
    lds[t] = v0;
    __syncthreads();
    for (int off = 1; off < 1024; off <<= 1) {
        int v = (t >= off) ? lds[t - off] : 0;
        __syncthreads();
        lds[t] += v;
        __syncthreads();
    }
    if (t < nb) partials[t] = lds[t] - v0;   // exclusive
    if (t == 1023) offsets[N] = lds[1023];
}

// scan phase C: intra-block exclusive scan + block base
__global__ void __launch_bounds__(SB) k_scan_final(const int* __restrict__ counts_in,
                                                   const int* __restrict__ partials,
                                                   int* __restrict__ offsets,
                                                   int* __restrict__ cursor, int N) {
    __shared__ int lds[SB];
    int t = threadIdx.x;
    int i = blockIdx.x * SB + t;
    int c = (i < N) ? counts_in[i] : 0;
    lds[t] = c;
    __syncthreads();
    for (int off = 1; off < SB; off <<= 1) {
        int v = (t >= off) ? lds[t - off] : 0;
        __syncthreads();
        lds[t] += v;
        __syncthreads();
    }
    int excl = lds[t] - c + partials[blockIdx.x];
    if (i < N) {
        offsets[i] = excl;
        cursor[i] = excl;
    }
}

// dst-range-partitioned reorder (XCD-local writes)
__global__ void __launch_bounds__(256) k_reorder(const int* __restrict__ adj,
                                                 int* __restrict__ cursor,
                                                 int* __restrict__ sorted_nbr, int E, int N) {
    int r = blockIdx.x & 7;
    int sub = blockIdx.x >> 3;
    int nsub = gridDim.x >> 3;
    int lo = N / 8 * r + min(r, N % 8);
    int hi = lo + N / 8 + (r < N % 8 ? 1 : 0);
    for (int e = sub * 256 + threadIdx.x; e < E; e += nsub * 256) {
        int d = adj[e];
        if (d < lo || d >= hi) continue;
        int nb = adj[E + e];
        int pos = atomicAdd(&cursor[d], 1);
        sorted_nbr[pos] = ((unsigned)nb < (unsigned)N) ? nb : 0;
    }
}

// one wave per destination; gathers bf16 Y rows (256 B), fp32 accumulate, fp32 mean -> FINAL out
__global__ void __launch_bounds__(256) k_aggregate_bf(const u32* __restrict__ Yb,
                                                      const int* __restrict__ offsets,
                                                      const int* __restrict__ sorted_nbr,
                                                      float2* __restrict__ out2, int N) {
    int wid = (blockIdx.x * blockDim.x + threadIdx.x) >> 6;
    int lane = threadIdx.x & 63;                 // lane holds dims 2*lane, 2*lane+1
    if (wid >= N) return;
    int beg = offsets[wid], end = offsets[wid + 1];
    float2 s = bfu(Yb[(size_t)wid * 64 + lane]);  // self edge
    float2 acc = make_float2(s.x, s.y);
    int e = beg;
    for (; e + 7 < end; e += 8) {                 // 8-way unroll: loads in flight
        int n0 = sorted_nbr[e],     n1 = sorted_nbr[e + 1];
        int n2 = sorted_nbr[e + 2], n3 = sorted_nbr[e + 3];
        int n4 = sorted_nbr[e + 4], n5 = sorted_nbr[e + 5];
        int n6 = sorted_nbr[e + 6], n7 = sorted_nbr[e + 7];
        u32 u0 = Yb[(size_t)n0 * 64 + lane], u1 = Yb[(size_t)n1 * 64 + lane];
        u32 u2 = Yb[(size_t)n2 * 64 + lane], u3 = Yb[(size_t)n3 * 64 + lane];
        u32 u4 = Yb[(size_t)n4 * 64 + lane], u5 = Yb[(size_t)n5 * 64 + lane];
        u32 u6 = Yb[(size_t)n6 * 64 + lane], u7 = Yb[(size_t)n7 * 64 + lane];
        float2 v0 = bfu(u0), v1 = bfu(u1), v2 = bfu(u2), v3 = bfu(u3);
        float2 v4 = bfu(u4), v5 = bfu(u5), v6 = bfu(u6), v7 = bfu(u7);
        acc.x += ((v0.x + v1.x) + (v2.x + v3.x)) + ((v4.x + v5.x) + (v6.x + v7.x));
        acc.y += ((v0.y + v1.y) + (v2.y + v3.y)) + ((v4.y + v5.y) + (v6.y + v7.y));
    }
    for (; e < end; ++e) {
        float2 v = bfu(Yb[(size_t)sorted_nbr[e] * 64 + lane]);
        acc.x += v.x;
        acc.y += v.y;
    }
    float inv = 1.0f / (float)(end - beg + 1);
    out2[(size_t)wid * 64 + lane] = make_float2(acc.x * inv, acc.y * inv);
}

extern "C" void kernel_launch(void* const* d_in, const int* in_sizes, int n_in,
                              void* d_out, int out_size, void* d_ws, size_t ws_size,
                              hipStream_t stream) {
    int N = in_sizes[0] / DIM;   // 100000
    int E = in_sizes[1] / 2;     // 1600000
    const float* X = (const float*)d_in[0];
    const int* adj = (const int*)d_in[1];
    const float* W = (const float*)d_in[2];
    float* out = (float*)d_out;

    int nb = (N + SB - 1) / SB;  // 391 scan blocks

    // ws: cursor[N] | offsets[N+1] | sorted_nbr[E] | partials[512] | Ybf[N*DIM u16] (~33 MB)
    int* cursor     = (int*)d_ws;
    int* offsets    = cursor + N;
    int* sorted_nbr = offsets + (N + 1);
    int* partials   = sorted_nbr + E;
    u16* Ybf        = (u16*)(partials + 512);

    int gemm_blocks = (N + 63) / 64;   // 64 rows/block (4 waves x 16)
    k_gemm_y<<<gemm_blocks, 256, 0, stream>>>((const float4*)X, W, Ybf, cursor, N);

    k_hist<<<1024, 256, 0, stream>>>(adj, cursor, E, N);
    k_bsum<<<nb, SB, 0, stream>>>(cursor, partials, N);
    k_pscan<<<1, 1024, 0, stream>>>(partials, offsets, nb, N);
    k_scan_final<<<nb, SB, 0, stream>>>(cursor, partials, offsets, cursor, N);
    k_reorder<<<1024, 256, 0, stream>>>(adj, cursor, sorted_nbr, E, N);

    int agg_blocks = (N + 3) / 4;   // one wave per destination, 4 waves/block
    k_aggregate_bf<<<agg_blocks, 256, 0, stream>>>((const u32*)Ybf, offsets, sorted_nbr,
                                                   (float2*)out, N);
}